// Round 1
// 466.073 us; speedup vs baseline: 1.0420x; 1.0420x over previous
//
#include <hip/hip_runtime.h>

// Masked-DCT round trip collapses algebraically. With orthonormal DCT D
// (D^T D = I) and P_low = diag(1,1,1,1,0,0,0,0):
//   coeffs = D^T s D,  corner_kl = P_k coeffs P_l,  img = D corner D^T
//   => img_c = (D P_k D^T) s (D P_l D^T) = G_k s G_l,  G_high = I - G_low.
// So with A = G s (vertical projection) and B = s - A:
//   c0 = A G, c1 = A - A G, c2 = B G, c3 = B - B G.
// G = D P_low D^T is symmetric AND persymmetric: G[i][j] == G[7-i][7-j].
// Each 8x8 block is split across a lane pair (lane ^ 32): lanes 0-31 own image
// rows 0-3 (natural order), lanes 32-63 own rows 7-4 (REVERSED order). By
// persymmetry both halves then use the SAME compile-time G rows (no divergent
// indexing); the partner's column entries just enter in reversed order.
constexpr float kG[8][8] = {
  { 0.7517087183f,  0.3767087182f, -0.0310378601f, -0.1560378601f, -0.0207388351f,  0.1042611649f,  0.0500679770f, -0.0749320231f},
  { 0.3767087182f,  0.3439621399f,  0.2517087183f,  0.1042611649f, -0.0310378601f, -0.0749320231f, -0.0207388351f,  0.0500679770f},
  {-0.0310378601f,  0.2517087183f,  0.4792611650f,  0.3767087182f,  0.0500679770f, -0.1560378602f, -0.0749320231f,  0.1042611649f},
  {-0.1560378601f,  0.1042611649f,  0.3767087182f,  0.4250679770f,  0.2517087182f,  0.0500679770f, -0.0310378601f, -0.0207388351f},
  {-0.0207388351f, -0.0310378601f,  0.0500679770f,  0.2517087182f,  0.4250679770f,  0.3767087182f,  0.1042611649f, -0.1560378601f},
  { 0.1042611649f, -0.0749320231f, -0.1560378602f,  0.0500679770f,  0.3767087182f,  0.4792611650f,  0.2517087183f, -0.0310378601f},
  { 0.0500679770f, -0.0207388351f, -0.0749320231f, -0.0310378601f,  0.1042611649f,  0.2517087183f,  0.3439621399f,  0.3767087182f},
  {-0.0749320231f,  0.0500679770f,  0.1042611649f, -0.0207388351f, -0.1560378601f, -0.0310378601f,  0.3767087182f,  0.7517087183f},
};

#define NPLANES   96            // 32 * 3
#define IMG_W     512
#define PLANE_SZ  (512 * 512)
#define NBLOCKS   (NPLANES * 64 * 64)   // 393216 8x8 blocks
#define NTHREADS  (NBLOCKS * 2)         // 2 lanes per block (lane ^ 32 pair)

__global__ __launch_bounds__(256) void dct_corners_kernel(
    const float* __restrict__ x, float* __restrict__ out) {
  const int tid  = blockIdx.x * 256 + threadIdx.x;
  const int lane = threadIdx.x & 63;
  const int half = lane >> 5;                    // 0: rows 0..3; 1: rows 7..4 (reversed)
  const int bi   = ((tid >> 6) << 5) + (lane & 31);  // lanes l and l+32 share block bi
  const int p    = bi >> 12;                     // 4096 blocks per 512x512 plane
  const int blk  = bi & 4095;
  const int by   = blk >> 6;
  const int bx   = blk & 63;                     // lanes 0-31 -> consecutive bx (coalesced)

  const size_t pb = (size_t)p * PLANE_SZ + (size_t)(by * 8) * IMG_W + (size_t)(bx * 8);
  const float* src = x + pb;

  // ---- load own 4 rows (local row r -> image row: half ? 7-r : r) ----
  // Per instruction: lanes 0-31 cover one contiguous 1KB image-row span,
  // lanes 32-63 another -> fully coalesced.
  float s[4][8];
#pragma unroll
  for (int r = 0; r < 4; ++r) {
    const int ra = half ? (7 - r) : r;           // v_cndmask, not divergent
    const float4 a = *reinterpret_cast<const float4*>(src + (size_t)ra * IMG_W);
    const float4 c = *reinterpret_cast<const float4*>(src + (size_t)ra * IMG_W + 4);
    s[r][0] = a.x; s[r][1] = a.y; s[r][2] = a.z; s[r][3] = a.w;
    s[r][4] = c.x; s[r][5] = c.y; s[r][6] = c.z; s[r][7] = c.w;
  }

  // ---- vertical projection A_loc = (rows of G s) for own half ----
  // Full local column = {s[0..3], partner_s[3], partner_s[2], partner_s[1], partner_s[0]}
  // (identical indexing for both halves thanks to persymmetry of G).
  float A[4][8];
#pragma unroll
  for (int j = 0; j < 8; ++j) {
    const float o0 = __shfl_xor(s[0][j], 32, 64);
    const float o1 = __shfl_xor(s[1][j], 32, 64);
    const float o2 = __shfl_xor(s[2][j], 32, 64);
    const float o3 = __shfl_xor(s[3][j], 32, 64);
#pragma unroll
    for (int i = 0; i < 4; ++i) {
      float acc =      kG[i][0] * s[0][j];
      acc = fmaf(kG[i][1], s[1][j], acc);
      acc = fmaf(kG[i][2], s[2][j], acc);
      acc = fmaf(kG[i][3], s[3][j], acc);
      acc = fmaf(kG[i][4], o3, acc);
      acc = fmaf(kG[i][5], o2, acc);
      acc = fmaf(kG[i][6], o1, acc);
      acc = fmaf(kG[i][7], o0, acc);
      A[i][j] = acc;
    }
  }

  // ---- per own row: horizontal projection + 4 corner stores ----
  const size_t CS = (size_t)NPLANES * PLANE_SZ;  // corner stride in out
  float* od = out + pb;
#pragma unroll
  for (int i = 0; i < 4; ++i) {
    const int ra = half ? (7 - i) : i;
    float* row = od + (size_t)ra * IMG_W;

    float bv[8];
#pragma unroll
    for (int j = 0; j < 8; ++j) bv[j] = s[i][j] - A[i][j];  // B = s - A row

    float t0[8], t2[8];                                     // A*G row, B*G row
#pragma unroll
    for (int j = 0; j < 8; ++j) {
      float aA = A[i][0] * kG[0][j];
      float aB = bv[0]   * kG[0][j];
#pragma unroll
      for (int l = 1; l < 8; ++l) {
        aA = fmaf(A[i][l], kG[l][j], aA);
        aB = fmaf(bv[l],   kG[l][j], aB);
      }
      t0[j] = aA; t2[j] = aB;
    }

    // c0 = A G | c1 = A - A G | c2 = B G | c3 = B - B G
    *reinterpret_cast<float4*>(row)              = make_float4(t0[0], t0[1], t0[2], t0[3]);
    *reinterpret_cast<float4*>(row + 4)          = make_float4(t0[4], t0[5], t0[6], t0[7]);
    *reinterpret_cast<float4*>(row + CS)         = make_float4(A[i][0] - t0[0], A[i][1] - t0[1], A[i][2] - t0[2], A[i][3] - t0[3]);
    *reinterpret_cast<float4*>(row + CS + 4)     = make_float4(A[i][4] - t0[4], A[i][5] - t0[5], A[i][6] - t0[6], A[i][7] - t0[7]);
    *reinterpret_cast<float4*>(row + 2 * CS)     = make_float4(t2[0], t2[1], t2[2], t2[3]);
    *reinterpret_cast<float4*>(row + 2 * CS + 4) = make_float4(t2[4], t2[5], t2[6], t2[7]);
    *reinterpret_cast<float4*>(row + 3 * CS)     = make_float4(bv[0] - t2[0], bv[1] - t2[1], bv[2] - t2[2], bv[3] - t2[3]);
    *reinterpret_cast<float4*>(row + 3 * CS + 4) = make_float4(bv[4] - t2[4], bv[5] - t2[5], bv[6] - t2[6], bv[7] - t2[7]);
  }
}

extern "C" void kernel_launch(void* const* d_in, const int* in_sizes, int n_in,
                              void* d_out, int out_size, void* d_ws, size_t ws_size,
                              hipStream_t stream) {
  const float* x = (const float*)d_in[0];
  float* out = (float*)d_out;
  const int threads = 256;
  const int grid = NTHREADS / threads;   // 3072, exact -> no bounds check in kernel
  hipLaunchKernelGGL(dct_corners_kernel, dim3(grid), dim3(threads), 0, stream, x, out);
}